// Round 16
// baseline (282.427 us; speedup 1.0000x reference)
//
#include <hip/hip_runtime.h>
#include <math.h>

#define NEG_SLOPE 0.2f
#define POOL_CHUNKS 8
#define SOFF 8.0f   // fixed softmax shift: exp(p-SOFF); |p|<~20 -> f32-safe

typedef __attribute__((ext_vector_type(8))) short bf16x8;
typedef __attribute__((ext_vector_type(4))) float f32x4;

__device__ __forceinline__ unsigned f2bf_rne(float x) {
    unsigned u = __float_as_uint(x);
    return (u + 0x7fffu + ((u >> 16) & 1u)) >> 16;
}

__device__ __forceinline__ int bsearch_batch(
    const int* __restrict__ batch, int N, int b)
{
    int lo = 0, hi = N;
    while (lo < hi) {
        int mid = (lo + hi) >> 1;
        if (batch[mid] < b) lo = mid + 1; else hi = mid;
    }
    return lo;
}

// ---------------- setup: zero deg + pack x -> bf16 pairs (fused) -------------
__global__ __launch_bounds__(256) void setup_pack(
    const float* __restrict__ x, unsigned* __restrict__ xpk, int npk,
    int* __restrict__ deg, int N)
{
    int i = blockIdx.x * blockDim.x + threadIdx.x;
    if (i < N) deg[i] = 0;
    if (i < npk) {
        const float2 v = *(const float2*)&x[(size_t)i * 2];
        xpk[i] = f2bf_rne(v.x) | (f2bf_rne(v.y) << 16);
    }
}

// ---------------- node GEMM via MFMA (A packed bf16, B single bf16) ----------
__global__ __launch_bounds__(256, 1) void node_gemm(
    const unsigned* __restrict__ hpk, const float* __restrict__ Wl,
    const float* __restrict__ Wr, unsigned* __restrict__ xlb,
    unsigned* __restrict__ xrb, int N, int nTiles)
{
    const int w   = threadIdx.x >> 6;
    const int l   = threadIdx.x & 63;
    const int l15 = l & 15, lg = l >> 4;

    const float* __restrict__ Wsel = (w < 2) ? Wl : Wr;
    unsigned* __restrict__ osel = (w < 2) ? xlb : xrb;
    const int cbase = (w & 1) * 64;

    bf16x8 bh[4][4];
    #pragma unroll
    for (int ct = 0; ct < 4; ++ct) {
        const int c = cbase + ct * 16 + l15;
        #pragma unroll
        for (int kt = 0; kt < 4; ++kt) {
            #pragma unroll
            for (int i = 0; i < 8; ++i) {
                float v = Wsel[(kt * 32 + lg * 8 + i) * 128 + c];
                bh[ct][kt][i] = (short)f2bf_rne(v);
            }
        }
    }

    for (int tile = blockIdx.x; tile < nTiles; tile += gridDim.x) {
        const int row0 = tile * 64;

        f32x4 acc[4][4];
        #pragma unroll
        for (int rt = 0; rt < 4; ++rt)
            #pragma unroll
            for (int ct = 0; ct < 4; ++ct)
                acc[rt][ct] = (f32x4){0.f, 0.f, 0.f, 0.f};

        #pragma unroll
        for (int rt = 0; rt < 4; ++rt) {
            int row = row0 + rt * 16 + l15;
            int rowc = row < N ? row : N - 1;
            bf16x8 ah[4];
            #pragma unroll
            for (int kt = 0; kt < 4; ++kt)
                ah[kt] = *(const bf16x8*)&hpk[(size_t)rowc * 64 + kt * 16 + lg * 4];
            #pragma unroll
            for (int kt = 0; kt < 4; ++kt) {
                #pragma unroll
                for (int ct = 0; ct < 4; ++ct) {
                    acc[rt][ct] = __builtin_amdgcn_mfma_f32_16x16x32_bf16(
                        ah[kt], bh[ct][kt], acc[rt][ct], 0, 0, 0);
                }
            }
        }

        #pragma unroll
        for (int rt = 0; rt < 4; ++rt) {
            #pragma unroll
            for (int ct = 0; ct < 4; ++ct) {
                #pragma unroll
                for (int j = 0; j < 4; ++j) {
                    int row = row0 + rt * 16 + lg * 4 + j;
                    unsigned o = f2bf_rne(acc[rt][ct][j]);
                    unsigned pr = (unsigned)__shfl_xor((int)o, 1);
                    if (!(l15 & 1) && row < N) {
                        int cp = (cbase + ct * 16 + l15) >> 1;
                        osel[(size_t)row * 64 + cp] = o | (pr << 16);
                    }
                }
            }
        }
    }
}

// ---------------- CSR build ---------------------------------------------------
__global__ __launch_bounds__(256) void edge_hist(
    const int* __restrict__ ei, int* __restrict__ deg, int E)
{
    int eid = blockIdx.x * blockDim.x + threadIdx.x;
    if (eid >= E) return;
    atomicAdd(&deg[ei[E + eid]], 1);
}

__global__ __launch_bounds__(256) void scan_block(
    const int* __restrict__ in, int* __restrict__ out_excl,
    int* __restrict__ bsum, int N)
{
    __shared__ int sm[256];
    int t = threadIdx.x, i = blockIdx.x * 256 + t;
    int v = (i < N) ? in[i] : 0;
    sm[t] = v;
    __syncthreads();
    int x = v;
    for (int o = 1; o < 256; o <<= 1) {
        int u = (t >= o) ? sm[t - o] : 0;
        __syncthreads();
        x += u; sm[t] = x;
        __syncthreads();
    }
    if (i < N) out_excl[i] = x - v;
    if (t == 255) bsum[blockIdx.x] = x;
}

__global__ __launch_bounds__(256) void scan_sums(int* __restrict__ bsum, int nb)
{
    __shared__ int sm[256];
    int t = threadIdx.x;
    int v = (t < nb) ? bsum[t] : 0;
    sm[t] = v;
    __syncthreads();
    int x = v;
    for (int o = 1; o < 256; o <<= 1) {
        int u = (t >= o) ? sm[t - o] : 0;
        __syncthreads();
        x += u; sm[t] = x;
        __syncthreads();
    }
    if (t < nb) bsum[t] = x - v;
}

__global__ __launch_bounds__(256) void scan_final(
    const int* __restrict__ excl, const int* __restrict__ bsum,
    int* __restrict__ rowptr, int* __restrict__ cursor, int N, int E)
{
    int i = blockIdx.x * blockDim.x + threadIdx.x;
    if (i > N) return;
    int v = (i < N) ? (excl[i] + bsum[i >> 8]) : E;
    rowptr[i] = v;
    if (i < N) cursor[i] = v;
}

__global__ __launch_bounds__(256) void edge_fill(
    const int* __restrict__ ei, int* __restrict__ cursor,
    unsigned short* __restrict__ srcs, int E)
{
    int eid = blockIdx.x * blockDim.x + threadIdx.x;
    if (eid >= E) return;
    int src = ei[eid], dst = ei[E + eid];
    int pos = atomicAdd(&cursor[dst], 1);
    __builtin_nontemporal_store((unsigned short)src, &srcs[pos]);
}

// ---------------- fused GATv2 aggregate --------------------------------------
__global__ __launch_bounds__(256) void gatv2_aggregate(
    const unsigned* __restrict__ xlb, const unsigned* __restrict__ xrb,
    const int* __restrict__ rowptr, const unsigned short* __restrict__ srcs,
    const float* __restrict__ att, const float* __restrict__ b,
    unsigned* __restrict__ hout, int N, int do_relu)
{
    int n = blockIdx.x * 4 + (threadIdx.x >> 6);
    if (n >= N) return;
    const int lane = threadIdx.x & 63;
    const int hl = lane & 15;
    const int g  = lane >> 4;

    auto unpack = [](const uint4 q, float* vv) {
        unsigned u;
        u = q.x; vv[0] = __uint_as_float(u << 16); vv[1] = __uint_as_float(u & 0xFFFF0000u);
        u = q.y; vv[2] = __uint_as_float(u << 16); vv[3] = __uint_as_float(u & 0xFFFF0000u);
        u = q.z; vv[4] = __uint_as_float(u << 16); vv[5] = __uint_as_float(u & 0xFFFF0000u);
        u = q.w; vv[6] = __uint_as_float(u << 16); vv[7] = __uint_as_float(u & 0xFFFF0000u);
    };

    float xr8[8], at8[8];
    {
        const uint4 qx = *(const uint4*)&xrb[(size_t)n * 64 + hl * 4];
        unpack(qx, xr8);
        const float4 t0 = *(const float4*)&att[hl * 8];
        const float4 t1 = *(const float4*)&att[hl * 8 + 4];
        at8[0]=t0.x; at8[1]=t0.y; at8[2]=t0.z; at8[3]=t0.w;
        at8[4]=t1.x; at8[5]=t1.y; at8[6]=t1.z; at8[7]=t1.w;
    }

    int r0 = rowptr[n], r1 = rowptr[n + 1];
    float s = 0.f;
    float acc[8];
    #pragma unroll
    for (int c = 0; c < 8; ++c) acc[c] = 0.f;

    auto score = [&](const float* vv) -> float {
        float p = 0.f;
        #pragma unroll
        for (int c = 0; c < 8; ++c) {
            float t = vv[c] + xr8[c];
            t = fmaxf(t, NEG_SLOPE * t);
            p += t * at8[c];
        }
        return p;
    };
    auto online = [&](float p, const float* vv) {
        float w = __expf(p - SOFF);
        s += w;
        #pragma unroll
        for (int c = 0; c < 8; ++c) acc[c] += w * vv[c];
    };

    if (g == 0) {
        const uint4 qs = *(const uint4*)&xlb[(size_t)n * 64 + hl * 4];
        float vs[8];
        unpack(qs, vs);
        float ps = score(vs);
        #pragma unroll
        for (int off = 1; off < 16; off <<= 1) ps += __shfl_xor(ps, off);
        online(ps, vs);
    }

    int j = r0 + g;
    int sa = (j < r1) ? (int)srcs[j] : 0;
    int sb = (j + 4 < r1) ? (int)srcs[j + 4] : sa;
    uint4 qa = *(const uint4*)&xlb[(size_t)sa * 64 + hl * 4];
    uint4 qb = *(const uint4*)&xlb[(size_t)sb * 64 + hl * 4];
    for (; j + 4 < r1; j += 8) {
        int jn0 = (j + 8  < r1) ? j + 8  : j;
        int jn1 = (j + 12 < r1) ? j + 12 : j;
        int sna = (int)srcs[jn0], snb = (int)srcs[jn1];
        uint4 qna = *(const uint4*)&xlb[(size_t)sna * 64 + hl * 4];
        uint4 qnb = *(const uint4*)&xlb[(size_t)snb * 64 + hl * 4];
        float va[8], vb[8];
        unpack(qa, va); unpack(qb, vb);
        float pa = score(va), pb = score(vb);
        #pragma unroll
        for (int off = 1; off < 16; off <<= 1) {
            pa += __shfl_xor(pa, off);
            pb += __shfl_xor(pb, off);
        }
        online(pa, va);
        online(pb, vb);
        qa = qna; qb = qnb;
    }
    if (j < r1) {
        float va[8];
        unpack(qa, va);
        float pa = score(va);
        #pragma unroll
        for (int off = 1; off < 16; off <<= 1) pa += __shfl_xor(pa, off);
        online(pa, va);
    }

    s += __shfl_xor(s, 16); s += __shfl_xor(s, 32);
    #pragma unroll
    for (int c = 0; c < 8; ++c) {
        acc[c] += __shfl_xor(acc[c], 16);
        acc[c] += __shfl_xor(acc[c], 32);
    }

    if (g == 0) {
        float inv = 1.f / s;
        unsigned pk[4];
        #pragma unroll
        for (int c = 0; c < 4; ++c) {
            float o0 = acc[2 * c]     * inv + b[hl * 8 + 2 * c];
            float o1 = acc[2 * c + 1] * inv + b[hl * 8 + 2 * c + 1];
            if (do_relu) { o0 = fmaxf(o0, 0.f); o1 = fmaxf(o1, 0.f); }
            pk[c] = f2bf_rne(o0) | (f2bf_rne(o1) << 16);
        }
        *(uint4*)&hout[(size_t)n * 64 + hl * 4] = make_uint4(pk[0], pk[1], pk[2], pk[3]);
    }
}

// ---------------- pooling (bounds inline via binary search) ------------------
__global__ __launch_bounds__(256) void pool_graph(
    const unsigned* __restrict__ h, const int* __restrict__ batch,
    float* __restrict__ pooled, int N)
{
    __shared__ float sm0[4][64];
    __shared__ float sm1[4][64];
    __shared__ int bounds[2];
    const int b = blockIdx.x / POOL_CHUNKS;
    const int chunk = blockIdx.x % POOL_CHUNKS;
    const int t = threadIdx.x;
    if (t < 2) bounds[t] = bsearch_batch(batch, N, b + t);
    __syncthreads();
    const int colp = t & 63, part = t >> 6;
    const int r0 = bounds[0], r1 = bounds[1];
    const int len = r1 - r0;
    const int c0 = r0 + (int)(((long long)len * chunk) / POOL_CHUNKS);
    const int c1 = r0 + (int)(((long long)len * (chunk + 1)) / POOL_CHUNKS);
    float s0 = 0.f, s1 = 0.f;
    for (int r = c0 + part; r < c1; r += 4) {
        unsigned u = h[(size_t)r * 64 + colp];
        s0 += __uint_as_float(u << 16);
        s1 += __uint_as_float(u & 0xFFFF0000u);
    }
    sm0[part][colp] = s0;
    sm1[part][colp] = s1;
    __syncthreads();
    if (part == 0) {
        #pragma unroll
        for (int p = 1; p < 4; ++p) { s0 += sm0[p][colp]; s1 += sm1[p][colp]; }
        float* dst = &pooled[(size_t)(b * POOL_CHUNKS + chunk) * 128 + colp * 2];
        dst[0] = s0; dst[1] = s1;
    }
}

// ---------------- MLP head (bounds inline) -----------------------------------
__global__ __launch_bounds__(256) void mlp_head(
    const float* __restrict__ pooled, const int* __restrict__ batch,
    const int* __restrict__ day, const int* __restrict__ hour,
    const float* __restrict__ day_tab, const float* __restrict__ hour_tab,
    const float* __restrict__ W1, const float* __restrict__ bl1,
    const float* __restrict__ W2, const float* __restrict__ bl2,
    const float* __restrict__ W3, const float* __restrict__ bl3,
    float* __restrict__ out, int N)
{
    __shared__ float f0[256], f1[256];
    __shared__ int bounds[2];
    const int b = blockIdx.x, t = threadIdx.x;
    if (t < 2) bounds[t] = bsearch_batch(batch, N, b + t);
    __syncthreads();
    float c = fmaxf((float)(bounds[1] - bounds[0]), 1.f);
    if (t < 128) {
        float sum = 0.f;
        #pragma unroll
        for (int ch = 0; ch < POOL_CHUNKS; ++ch)
            sum += pooled[(size_t)(b * POOL_CHUNKS + ch) * 128 + t];
        f0[t] = sum / c;
    }
    else if (t < 192) f0[t] = day_tab[day[b] * 64 + (t - 128)];
    else              f0[t] = hour_tab[hour[b] * 64 + (t - 192)];
    __syncthreads();
    float a = bl1[t];
    for (int k = 0; k < 256; ++k) a += f0[k] * W1[k * 256 + t];
    f1[t] = a > 0.f ? a : 0.f;
    __syncthreads();
    a = bl2[t];
    for (int k = 0; k < 256; ++k) a += f1[k] * W2[k * 256 + t];
    __syncthreads();
    f0[t] = a > 0.f ? a : 0.f;
    __syncthreads();
    f1[t] = f0[t] * W3[t];
    __syncthreads();
    for (int s2 = 128; s2 > 0; s2 >>= 1) {
        if (t < s2) f1[t] += f1[t + s2];
        __syncthreads();
    }
    if (t == 0) out[b] = f1[0] + bl3[0];
}

extern "C" void kernel_launch(void* const* d_in, const int* in_sizes, int n_in,
                              void* d_out, int out_size, void* d_ws, size_t ws_size,
                              hipStream_t stream) {
    const float* x        = (const float*)d_in[0];
    const int*   ei       = (const int*)d_in[1];
    const int*   batch    = (const int*)d_in[2];
    const int*   day      = (const int*)d_in[3];
    const int*   hour     = (const int*)d_in[4];
    const float* Wl[3]  = { (const float*)d_in[5],  (const float*)d_in[9],  (const float*)d_in[13] };
    const float* Wr[3]  = { (const float*)d_in[6],  (const float*)d_in[10], (const float*)d_in[14] };
    const float* att[3] = { (const float*)d_in[7],  (const float*)d_in[11], (const float*)d_in[15] };
    const float* bb[3]  = { (const float*)d_in[8],  (const float*)d_in[12], (const float*)d_in[16] };
    const float* day_tab  = (const float*)d_in[17];
    const float* hour_tab = (const float*)d_in[18];
    const float* W1 = (const float*)d_in[19]; const float* bl1 = (const float*)d_in[20];
    const float* W2 = (const float*)d_in[21]; const float* bl2 = (const float*)d_in[22];
    const float* W3 = (const float*)d_in[23]; const float* bl3 = (const float*)d_in[24];
    float* out = (float*)d_out;

    const int N  = in_sizes[0] / 128;
    const int E  = in_sizes[1] / 2;
    const int B  = in_sizes[3];

    char* ws = (char*)d_ws;
    size_t off = 0;
    auto alloc = [&](size_t bytes) -> void* {
        void* p = ws + off;
        off += (bytes + 255) & ~(size_t)255;
        return p;
    };
    const size_t NPK = (size_t)N * 64 * sizeof(unsigned);
    unsigned* xpk  = (unsigned*)alloc(NPK);
    unsigned* xlb  = (unsigned*)alloc(NPK);
    unsigned* xrb  = (unsigned*)alloc(NPK);
    unsigned* hbuf = (unsigned*)alloc(NPK);
    int*   deg    = (int*)alloc((size_t)N * sizeof(int));
    int*   excl   = (int*)alloc((size_t)N * sizeof(int));
    int*   bsum   = (int*)alloc(256 * sizeof(int));
    int*   rowptr = (int*)alloc((size_t)(N + 1) * sizeof(int));
    int*   cursor = (int*)alloc((size_t)N * sizeof(int));
    unsigned short* srcs = (unsigned short*)alloc((size_t)E * sizeof(unsigned short));
    float* pooled = (float*)alloc((size_t)B * POOL_CHUNKS * 128 * sizeof(float));
    (void)ws_size;

    const int nb = (N + 255) / 256;
    const int edge_grid  = (E + 255) / 256;
    const int node_grid4 = (N + 3) / 4;
    const int nTiles     = (N + 63) / 64;
    const int setup_grid = (N * 64 + 255) / 256;   // covers both zero and pack

    // ---- setup (zero deg + pack x) + CSR build ----
    setup_pack<<<setup_grid, 256, 0, stream>>>(x, xpk, N * 64, deg, N);
    edge_hist<<<edge_grid, 256, 0, stream>>>(ei, deg, E);
    scan_block<<<nb, 256, 0, stream>>>(deg, excl, bsum, N);
    scan_sums<<<1, 256, 0, stream>>>(bsum, nb);
    scan_final<<<(N + 256) / 256, 256, 0, stream>>>(excl, bsum, rowptr, cursor, N, E);
    edge_fill<<<edge_grid, 256, 0, stream>>>(ei, cursor, srcs, E);

    // ---- 3 GATv2 layers (h carried as packed bf16) ----
    const unsigned* hin = xpk;
    for (int l = 0; l < 3; ++l) {
        node_gemm<<<nTiles, 256, 0, stream>>>(hin, Wl[l], Wr[l], xlb, xrb, N, nTiles);
        gatv2_aggregate<<<node_grid4, 256, 0, stream>>>(
            xlb, xrb, rowptr, srcs, att[l], bb[l], hbuf, N, l < 2 ? 1 : 0);
        hin = hbuf;
    }

    // ---- pool + head ----
    pool_graph<<<B * POOL_CHUNKS, 256, 0, stream>>>(hbuf, batch, pooled, N);
    mlp_head<<<B, 256, 0, stream>>>(pooled, batch, day, hour, day_tab, hour_tab,
                                    W1, bl1, W2, bl2, W3, bl3, out, N);
}

// Round 17
// 265.744 us; speedup vs baseline: 1.0628x; 1.0628x over previous
//
#include <hip/hip_runtime.h>
#include <math.h>

#define NEG_SLOPE 0.2f
#define POOL_CHUNKS 8
#define SOFF 8.0f   // fixed softmax shift: exp(p-SOFF); |p|<~20 -> f32-safe

typedef __attribute__((ext_vector_type(8))) short bf16x8;
typedef __attribute__((ext_vector_type(4))) float f32x4;

__device__ __forceinline__ unsigned f2bf_rne(float x) {
    unsigned u = __float_as_uint(x);
    return (u + 0x7fffu + ((u >> 16) & 1u)) >> 16;
}

__device__ __forceinline__ int bsearch_batch(
    const int* __restrict__ batch, int N, int b)
{
    int lo = 0, hi = N;
    while (lo < hi) {
        int mid = (lo + hi) >> 1;
        if (batch[mid] < b) lo = mid + 1; else hi = mid;
    }
    return lo;
}

// ---------------- setup: zero deg + pack x -> bf16 pairs (fused) -------------
__global__ __launch_bounds__(256) void setup_pack(
    const float* __restrict__ x, unsigned* __restrict__ xpk, int npk,
    int* __restrict__ deg, int N)
{
    int i = blockIdx.x * blockDim.x + threadIdx.x;
    if (i < N) deg[i] = 0;
    if (i < npk) {
        const float2 v = *(const float2*)&x[(size_t)i * 2];
        xpk[i] = f2bf_rne(v.x) | (f2bf_rne(v.y) << 16);
    }
}

// ---------------- node GEMM via MFMA (A packed bf16, B single bf16) ----------
__global__ __launch_bounds__(256, 1) void node_gemm(
    const unsigned* __restrict__ hpk, const float* __restrict__ Wl,
    const float* __restrict__ Wr, unsigned* __restrict__ xlb,
    unsigned* __restrict__ xrb, int N, int nTiles)
{
    const int w   = threadIdx.x >> 6;
    const int l   = threadIdx.x & 63;
    const int l15 = l & 15, lg = l >> 4;

    const float* __restrict__ Wsel = (w < 2) ? Wl : Wr;
    unsigned* __restrict__ osel = (w < 2) ? xlb : xrb;
    const int cbase = (w & 1) * 64;

    bf16x8 bh[4][4];
    #pragma unroll
    for (int ct = 0; ct < 4; ++ct) {
        const int c = cbase + ct * 16 + l15;
        #pragma unroll
        for (int kt = 0; kt < 4; ++kt) {
            #pragma unroll
            for (int i = 0; i < 8; ++i) {
                float v = Wsel[(kt * 32 + lg * 8 + i) * 128 + c];
                bh[ct][kt][i] = (short)f2bf_rne(v);
            }
        }
    }

    for (int tile = blockIdx.x; tile < nTiles; tile += gridDim.x) {
        const int row0 = tile * 64;

        f32x4 acc[4][4];
        #pragma unroll
        for (int rt = 0; rt < 4; ++rt)
            #pragma unroll
            for (int ct = 0; ct < 4; ++ct)
                acc[rt][ct] = (f32x4){0.f, 0.f, 0.f, 0.f};

        #pragma unroll
        for (int rt = 0; rt < 4; ++rt) {
            int row = row0 + rt * 16 + l15;
            int rowc = row < N ? row : N - 1;
            bf16x8 ah[4];
            #pragma unroll
            for (int kt = 0; kt < 4; ++kt)
                ah[kt] = *(const bf16x8*)&hpk[(size_t)rowc * 64 + kt * 16 + lg * 4];
            #pragma unroll
            for (int kt = 0; kt < 4; ++kt) {
                #pragma unroll
                for (int ct = 0; ct < 4; ++ct) {
                    acc[rt][ct] = __builtin_amdgcn_mfma_f32_16x16x32_bf16(
                        ah[kt], bh[ct][kt], acc[rt][ct], 0, 0, 0);
                }
            }
        }

        #pragma unroll
        for (int rt = 0; rt < 4; ++rt) {
            #pragma unroll
            for (int ct = 0; ct < 4; ++ct) {
                #pragma unroll
                for (int j = 0; j < 4; ++j) {
                    int row = row0 + rt * 16 + lg * 4 + j;
                    unsigned o = f2bf_rne(acc[rt][ct][j]);
                    unsigned pr = (unsigned)__shfl_xor((int)o, 1);
                    if (!(l15 & 1) && row < N) {
                        int cp = (cbase + ct * 16 + l15) >> 1;
                        osel[(size_t)row * 64 + cp] = o | (pr << 16);
                    }
                }
            }
        }
    }
}

// ---------------- CSR build ---------------------------------------------------
__global__ __launch_bounds__(256) void edge_hist(
    const int* __restrict__ ei, int* __restrict__ deg, int E)
{
    int eid = blockIdx.x * blockDim.x + threadIdx.x;
    if (eid >= E) return;
    atomicAdd(&deg[ei[E + eid]], 1);
}

__global__ __launch_bounds__(256) void scan_block(
    const int* __restrict__ in, int* __restrict__ out_excl,
    int* __restrict__ bsum, int N)
{
    __shared__ int sm[256];
    int t = threadIdx.x, i = blockIdx.x * 256 + t;
    int v = (i < N) ? in[i] : 0;
    sm[t] = v;
    __syncthreads();
    int x = v;
    for (int o = 1; o < 256; o <<= 1) {
        int u = (t >= o) ? sm[t - o] : 0;
        __syncthreads();
        x += u; sm[t] = x;
        __syncthreads();
    }
    if (i < N) out_excl[i] = x - v;
    if (t == 255) bsum[blockIdx.x] = x;
}

__global__ __launch_bounds__(256) void scan_sums(int* __restrict__ bsum, int nb)
{
    __shared__ int sm[256];
    int t = threadIdx.x;
    int v = (t < nb) ? bsum[t] : 0;
    sm[t] = v;
    __syncthreads();
    int x = v;
    for (int o = 1; o < 256; o <<= 1) {
        int u = (t >= o) ? sm[t - o] : 0;
        __syncthreads();
        x += u; sm[t] = x;
        __syncthreads();
    }
    if (t < nb) bsum[t] = x - v;
}

__global__ __launch_bounds__(256) void scan_final(
    const int* __restrict__ excl, const int* __restrict__ bsum,
    int* __restrict__ rowptr, int* __restrict__ cursor, int N, int E)
{
    int i = blockIdx.x * blockDim.x + threadIdx.x;
    if (i > N) return;
    int v = (i < N) ? (excl[i] + bsum[i >> 8]) : E;
    rowptr[i] = v;
    if (i < N) cursor[i] = v;
}

__global__ __launch_bounds__(256) void edge_fill(
    const int* __restrict__ ei, int* __restrict__ cursor,
    unsigned short* __restrict__ srcs, int E)
{
    int eid = blockIdx.x * blockDim.x + threadIdx.x;
    if (eid >= E) return;
    int src = ei[eid], dst = ei[E + eid];
    int pos = atomicAdd(&cursor[dst], 1);
    srcs[pos] = (unsigned short)src;   // plain store: L2 absorbs/merges partial lines
}

// ---------------- fused GATv2 aggregate --------------------------------------
__global__ __launch_bounds__(256) void gatv2_aggregate(
    const unsigned* __restrict__ xlb, const unsigned* __restrict__ xrb,
    const int* __restrict__ rowptr, const unsigned short* __restrict__ srcs,
    const float* __restrict__ att, const float* __restrict__ b,
    unsigned* __restrict__ hout, int N, int do_relu)
{
    int n = blockIdx.x * 4 + (threadIdx.x >> 6);
    if (n >= N) return;
    const int lane = threadIdx.x & 63;
    const int hl = lane & 15;
    const int g  = lane >> 4;

    auto unpack = [](const uint4 q, float* vv) {
        unsigned u;
        u = q.x; vv[0] = __uint_as_float(u << 16); vv[1] = __uint_as_float(u & 0xFFFF0000u);
        u = q.y; vv[2] = __uint_as_float(u << 16); vv[3] = __uint_as_float(u & 0xFFFF0000u);
        u = q.z; vv[4] = __uint_as_float(u << 16); vv[5] = __uint_as_float(u & 0xFFFF0000u);
        u = q.w; vv[6] = __uint_as_float(u << 16); vv[7] = __uint_as_float(u & 0xFFFF0000u);
    };

    float xr8[8], at8[8];
    {
        const uint4 qx = *(const uint4*)&xrb[(size_t)n * 64 + hl * 4];
        unpack(qx, xr8);
        const float4 t0 = *(const float4*)&att[hl * 8];
        const float4 t1 = *(const float4*)&att[hl * 8 + 4];
        at8[0]=t0.x; at8[1]=t0.y; at8[2]=t0.z; at8[3]=t0.w;
        at8[4]=t1.x; at8[5]=t1.y; at8[6]=t1.z; at8[7]=t1.w;
    }

    int r0 = rowptr[n], r1 = rowptr[n + 1];
    float s = 0.f;
    float acc[8];
    #pragma unroll
    for (int c = 0; c < 8; ++c) acc[c] = 0.f;

    auto score = [&](const float* vv) -> float {
        float p = 0.f;
        #pragma unroll
        for (int c = 0; c < 8; ++c) {
            float t = vv[c] + xr8[c];
            t = fmaxf(t, NEG_SLOPE * t);
            p += t * at8[c];
        }
        return p;
    };
    auto online = [&](float p, const float* vv) {
        float w = __expf(p - SOFF);
        s += w;
        #pragma unroll
        for (int c = 0; c < 8; ++c) acc[c] += w * vv[c];
    };

    if (g == 0) {
        const uint4 qs = *(const uint4*)&xlb[(size_t)n * 64 + hl * 4];
        float vs[8];
        unpack(qs, vs);
        float ps = score(vs);
        #pragma unroll
        for (int off = 1; off < 16; off <<= 1) ps += __shfl_xor(ps, off);
        online(ps, vs);
    }

    int j = r0 + g;
    int sa = (j < r1) ? (int)srcs[j] : 0;
    int sb = (j + 4 < r1) ? (int)srcs[j + 4] : sa;
    uint4 qa = *(const uint4*)&xlb[(size_t)sa * 64 + hl * 4];
    uint4 qb = *(const uint4*)&xlb[(size_t)sb * 64 + hl * 4];
    for (; j + 4 < r1; j += 8) {
        int jn0 = (j + 8  < r1) ? j + 8  : j;
        int jn1 = (j + 12 < r1) ? j + 12 : j;
        int sna = (int)srcs[jn0], snb = (int)srcs[jn1];
        uint4 qna = *(const uint4*)&xlb[(size_t)sna * 64 + hl * 4];
        uint4 qnb = *(const uint4*)&xlb[(size_t)snb * 64 + hl * 4];
        float va[8], vb[8];
        unpack(qa, va); unpack(qb, vb);
        float pa = score(va), pb = score(vb);
        #pragma unroll
        for (int off = 1; off < 16; off <<= 1) {
            pa += __shfl_xor(pa, off);
            pb += __shfl_xor(pb, off);
        }
        online(pa, va);
        online(pb, vb);
        qa = qna; qb = qnb;
    }
    if (j < r1) {
        float va[8];
        unpack(qa, va);
        float pa = score(va);
        #pragma unroll
        for (int off = 1; off < 16; off <<= 1) pa += __shfl_xor(pa, off);
        online(pa, va);
    }

    s += __shfl_xor(s, 16); s += __shfl_xor(s, 32);
    #pragma unroll
    for (int c = 0; c < 8; ++c) {
        acc[c] += __shfl_xor(acc[c], 16);
        acc[c] += __shfl_xor(acc[c], 32);
    }

    if (g == 0) {
        float inv = 1.f / s;
        unsigned pk[4];
        #pragma unroll
        for (int c = 0; c < 4; ++c) {
            float o0 = acc[2 * c]     * inv + b[hl * 8 + 2 * c];
            float o1 = acc[2 * c + 1] * inv + b[hl * 8 + 2 * c + 1];
            if (do_relu) { o0 = fmaxf(o0, 0.f); o1 = fmaxf(o1, 0.f); }
            pk[c] = f2bf_rne(o0) | (f2bf_rne(o1) << 16);
        }
        *(uint4*)&hout[(size_t)n * 64 + hl * 4] = make_uint4(pk[0], pk[1], pk[2], pk[3]);
    }
}

// ---------------- pooling (bounds inline via binary search) ------------------
__global__ __launch_bounds__(256) void pool_graph(
    const unsigned* __restrict__ h, const int* __restrict__ batch,
    float* __restrict__ pooled, int N)
{
    __shared__ float sm0[4][64];
    __shared__ float sm1[4][64];
    __shared__ int bounds[2];
    const int b = blockIdx.x / POOL_CHUNKS;
    const int chunk = blockIdx.x % POOL_CHUNKS;
    const int t = threadIdx.x;
    if (t < 2) bounds[t] = bsearch_batch(batch, N, b + t);
    __syncthreads();
    const int colp = t & 63, part = t >> 6;
    const int r0 = bounds[0], r1 = bounds[1];
    const int len = r1 - r0;
    const int c0 = r0 + (int)(((long long)len * chunk) / POOL_CHUNKS);
    const int c1 = r0 + (int)(((long long)len * (chunk + 1)) / POOL_CHUNKS);
    float s0 = 0.f, s1 = 0.f;
    for (int r = c0 + part; r < c1; r += 4) {
        unsigned u = h[(size_t)r * 64 + colp];
        s0 += __uint_as_float(u << 16);
        s1 += __uint_as_float(u & 0xFFFF0000u);
    }
    sm0[part][colp] = s0;
    sm1[part][colp] = s1;
    __syncthreads();
    if (part == 0) {
        #pragma unroll
        for (int p = 1; p < 4; ++p) { s0 += sm0[p][colp]; s1 += sm1[p][colp]; }
        float* dst = &pooled[(size_t)(b * POOL_CHUNKS + chunk) * 128 + colp * 2];
        dst[0] = s0; dst[1] = s1;
    }
}

// ---------------- MLP head (bounds inline) -----------------------------------
__global__ __launch_bounds__(256) void mlp_head(
    const float* __restrict__ pooled, const int* __restrict__ batch,
    const int* __restrict__ day, const int* __restrict__ hour,
    const float* __restrict__ day_tab, const float* __restrict__ hour_tab,
    const float* __restrict__ W1, const float* __restrict__ bl1,
    const float* __restrict__ W2, const float* __restrict__ bl2,
    const float* __restrict__ W3, const float* __restrict__ bl3,
    float* __restrict__ out, int N)
{
    __shared__ float f0[256], f1[256];
    __shared__ int bounds[2];
    const int b = blockIdx.x, t = threadIdx.x;
    if (t < 2) bounds[t] = bsearch_batch(batch, N, b + t);
    __syncthreads();
    float c = fmaxf((float)(bounds[1] - bounds[0]), 1.f);
    if (t < 128) {
        float sum = 0.f;
        #pragma unroll
        for (int ch = 0; ch < POOL_CHUNKS; ++ch)
            sum += pooled[(size_t)(b * POOL_CHUNKS + ch) * 128 + t];
        f0[t] = sum / c;
    }
    else if (t < 192) f0[t] = day_tab[day[b] * 64 + (t - 128)];
    else              f0[t] = hour_tab[hour[b] * 64 + (t - 192)];
    __syncthreads();
    float a = bl1[t];
    for (int k = 0; k < 256; ++k) a += f0[k] * W1[k * 256 + t];
    f1[t] = a > 0.f ? a : 0.f;
    __syncthreads();
    a = bl2[t];
    for (int k = 0; k < 256; ++k) a += f1[k] * W2[k * 256 + t];
    __syncthreads();
    f0[t] = a > 0.f ? a : 0.f;
    __syncthreads();
    f1[t] = f0[t] * W3[t];
    __syncthreads();
    for (int s2 = 128; s2 > 0; s2 >>= 1) {
        if (t < s2) f1[t] += f1[t + s2];
        __syncthreads();
    }
    if (t == 0) out[b] = f1[0] + bl3[0];
}

extern "C" void kernel_launch(void* const* d_in, const int* in_sizes, int n_in,
                              void* d_out, int out_size, void* d_ws, size_t ws_size,
                              hipStream_t stream) {
    const float* x        = (const float*)d_in[0];
    const int*   ei       = (const int*)d_in[1];
    const int*   batch    = (const int*)d_in[2];
    const int*   day      = (const int*)d_in[3];
    const int*   hour     = (const int*)d_in[4];
    const float* Wl[3]  = { (const float*)d_in[5],  (const float*)d_in[9],  (const float*)d_in[13] };
    const float* Wr[3]  = { (const float*)d_in[6],  (const float*)d_in[10], (const float*)d_in[14] };
    const float* att[3] = { (const float*)d_in[7],  (const float*)d_in[11], (const float*)d_in[15] };
    const float* bb[3]  = { (const float*)d_in[8],  (const float*)d_in[12], (const float*)d_in[16] };
    const float* day_tab  = (const float*)d_in[17];
    const float* hour_tab = (const float*)d_in[18];
    const float* W1 = (const float*)d_in[19]; const float* bl1 = (const float*)d_in[20];
    const float* W2 = (const float*)d_in[21]; const float* bl2 = (const float*)d_in[22];
    const float* W3 = (const float*)d_in[23]; const float* bl3 = (const float*)d_in[24];
    float* out = (float*)d_out;

    const int N  = in_sizes[0] / 128;
    const int E  = in_sizes[1] / 2;
    const int B  = in_sizes[3];

    char* ws = (char*)d_ws;
    size_t off = 0;
    auto alloc = [&](size_t bytes) -> void* {
        void* p = ws + off;
        off += (bytes + 255) & ~(size_t)255;
        return p;
    };
    const size_t NPK = (size_t)N * 64 * sizeof(unsigned);
    unsigned* xpk  = (unsigned*)alloc(NPK);
    unsigned* xlb  = (unsigned*)alloc(NPK);
    unsigned* xrb  = (unsigned*)alloc(NPK);
    unsigned* hbuf = (unsigned*)alloc(NPK);
    int*   deg    = (int*)alloc((size_t)N * sizeof(int));
    int*   excl   = (int*)alloc((size_t)N * sizeof(int));
    int*   bsum   = (int*)alloc(256 * sizeof(int));
    int*   rowptr = (int*)alloc((size_t)(N + 1) * sizeof(int));
    int*   cursor = (int*)alloc((size_t)N * sizeof(int));
    unsigned short* srcs = (unsigned short*)alloc((size_t)E * sizeof(unsigned short));
    float* pooled = (float*)alloc((size_t)B * POOL_CHUNKS * 128 * sizeof(float));
    (void)ws_size;

    const int nb = (N + 255) / 256;
    const int edge_grid  = (E + 255) / 256;
    const int node_grid4 = (N + 3) / 4;
    const int nTiles     = (N + 63) / 64;
    const int setup_grid = (N * 64 + 255) / 256;

    // ---- setup (zero deg + pack x) + CSR build ----
    setup_pack<<<setup_grid, 256, 0, stream>>>(x, xpk, N * 64, deg, N);
    edge_hist<<<edge_grid, 256, 0, stream>>>(ei, deg, E);
    scan_block<<<nb, 256, 0, stream>>>(deg, excl, bsum, N);
    scan_sums<<<1, 256, 0, stream>>>(bsum, nb);
    scan_final<<<(N + 256) / 256, 256, 0, stream>>>(excl, bsum, rowptr, cursor, N, E);
    edge_fill<<<edge_grid, 256, 0, stream>>>(ei, cursor, srcs, E);

    // ---- 3 GATv2 layers (h carried as packed bf16) ----
    const unsigned* hin = xpk;
    for (int l = 0; l < 3; ++l) {
        node_gemm<<<nTiles, 256, 0, stream>>>(hin, Wl[l], Wr[l], xlb, xrb, N, nTiles);
        gatv2_aggregate<<<node_grid4, 256, 0, stream>>>(
            xlb, xrb, rowptr, srcs, att[l], bb[l], hbuf, N, l < 2 ? 1 : 0);
        hin = hbuf;
    }

    // ---- pool + head ----
    pool_graph<<<B * POOL_CHUNKS, 256, 0, stream>>>(hbuf, batch, pooled, N);
    mlp_head<<<B, 256, 0, stream>>>(pooled, batch, day, hour, day_tab, hour_tab,
                                    W1, bl1, W2, bl2, W3, bl3, out, N);
}